// Round 7
// baseline (491.624 us; speedup 1.0000x reference)
//
#include <hip/hip_runtime.h>

// GLIFR RNN (B=64, T=200, IN=512, HID=1024, OUT=512), fp32 in/out, bf16 MFMA.
//
// Round 7: round-6 dataflow (block-local GEMM->LDS->recurrence, monotonic
// flags), but tiles split 32-ways in N (80x32, grid 512 = 16 btiles x 32
// ntiles). LDS ~49 KB -> 2 blocks/CU co-resident, so barrier-drain stalls of
// one block are covered by the other (round 6 had 1 block/CU, 11.5% occ,
// every k-tile paid full load latency serially -> 281 us). Readout is
// interleaved into the chain (chunk r=c-1 after flag release) to fill flag
// bubbles and delete the serial tail. Csm padded (stride 33) to kill the
// 4-way quad bank conflict (1.2M conflicts in round 6).
//
// Workspace (~44 MB):
//   F     bf16 [10][1280][1024] @ 0          (26214400 B)  rows b*20+s
//   xb    bf16 [10][1280][512]  @ 26214400   (13107200 B)  rows b*20+s
//   WinT  bf16 [1024][512]      @ 39321600   (1048576 B)
//   WlatT bf16 [1024][1024]     @ 40370176   (2097152 B)
//   WoutB bf16 [512][1024]      @ 42467328   (1048576 B)
//   flags u32  [10][16]+pad     @ 43515904   (1024 B)   count to 32

typedef float f32x4 __attribute__((ext_vector_type(4)));
typedef __bf16 bf16x8 __attribute__((ext_vector_type(8)));
typedef unsigned short ushortx8 __attribute__((ext_vector_type(8)));
typedef unsigned short ushortx4 __attribute__((ext_vector_type(4)));

__device__ __forceinline__ unsigned short f2b(float f) {
    unsigned int u = __float_as_uint(f);
    unsigned int r = u + 0x7FFFu + ((u >> 16) & 1u);   // RNE
    return (unsigned short)(r >> 16);
}
__device__ __forceinline__ float sigmoidf(float x) {
    return 1.0f / (1.0f + __expf(-x));
}

// async global->LDS, 16 B per lane; LDS dest is wave-uniform base + lane*16
__device__ __forceinline__ void gl_lds16(const unsigned short* g, unsigned short* l) {
    __builtin_amdgcn_global_load_lds(
        (const __attribute__((address_space(1))) void*)g,
        (__attribute__((address_space(3))) void*)l, 16, 0, 0);
}

// ---------------------------------------------------------------------------
// One prep kernel: W_in/W_lat transpose->bf16, W_out convert, x->xb reorder
// ([b][t][k] -> chunk rows b*20+s), flags zero.  Grid 4097 x 256.
// ---------------------------------------------------------------------------
__global__ __launch_bounds__(256) void prep(
    const float* __restrict__ x, const float* __restrict__ W_in,
    const float* __restrict__ W_lat, const float* __restrict__ W_out,
    unsigned short* __restrict__ xb, unsigned short* __restrict__ WinT,
    unsigned short* __restrict__ WlatT, unsigned short* __restrict__ WoutB,
    unsigned* __restrict__ flags)
{
    __shared__ unsigned short t[64][65];
    const int blk = blockIdx.x;
    if (blk < 384) {
        const float* in; unsigned short* outp; int R, C, bx, by;
        if (blk < 128) { in = W_in;  outp = WinT;  R = 512;  C = 1024;
                         bx = (blk & 15) * 64; by = (blk >> 4) * 64; }
        else { int i = blk - 128; in = W_lat; outp = WlatT; R = 1024; C = 1024;
               bx = (i & 15) * 64; by = (i >> 4) * 64; }
        int tx = threadIdx.x & 63, ty = threadIdx.x >> 6;
        for (int r = ty; r < 64; r += 4)
            t[r][tx] = f2b(in[(size_t)(by + r) * C + bx + tx]);
        __syncthreads();
        for (int r = ty; r < 64; r += 4)
            outp[(size_t)(bx + r) * R + by + tx] = t[tx][r];
    } else if (blk < 896) {
        int i = ((blk - 384) * 256 + threadIdx.x) * 4;     // 512*1024 elems
        f32x4 v = *(const f32x4*)(W_out + i);
        ushortx4 o;
        o[0] = f2b(v[0]); o[1] = f2b(v[1]); o[2] = f2b(v[2]); o[3] = f2b(v[3]);
        *(ushortx4*)(WoutB + i) = o;
    } else if (blk < 4096) {
        size_t i8 = (size_t)((blk - 896) * 256 + threadIdx.x) * 8;
        int g = (int)(i8 >> 9), k = (int)(i8 & 511);
        int c = g / 1280, rr = g - c * 1280, b = rr / 20, s = rr - b * 20;
        const float* src = x + ((size_t)b * 200 + c * 20 + s) * 512 + k;
        f32x4 v0 = *(const f32x4*)src, v1 = *(const f32x4*)(src + 4);
        ushortx8 o;
        o[0] = f2b(v0[0]); o[1] = f2b(v0[1]); o[2] = f2b(v0[2]); o[3] = f2b(v0[3]);
        o[4] = f2b(v1[0]); o[5] = f2b(v1[1]); o[6] = f2b(v1[2]); o[7] = f2b(v1[3]);
        *(ushortx8*)(xb + i8) = o;
    } else {
        flags[threadIdx.x] = 0u;     // 256 words cover the flag region
    }
}

// ---------------------------------------------------------------------------
// Fused GLIFR kernel. 512 blocks x 256 threads, 2 blocks/CU.
// btile = blk&15 (4 batches, 80 rows), ntile = blk>>4 in [0,32) (32 h-cols).
// Waves: kh = wave>>1 (k-half of 64-k tile), jt = wave&1 (16-col half).
// Per chunk: proj GEMM (K=512, no dep) -> flag wait -> lateral GEMM (K=1024)
// -> Csm(two kh planes, stride 33) -> 20-step recurrence (128 threads own
// the 4b x 32h states) -> F store -> release flag -> interleaved readout of
// chunk c-1 (oc-tile = ntile&15, chunk-half = ntile>>4).
// ---------------------------------------------------------------------------
__global__ __launch_bounds__(256, 2) void fused(
    const unsigned short* __restrict__ xb,
    const unsigned short* __restrict__ WinT,
    const unsigned short* __restrict__ WlatT,
    const unsigned short* __restrict__ WoutB,
    unsigned short* __restrict__ F,
    float* __restrict__ out,
    const float* __restrict__ thresh, const float* __restrict__ t_km,
    const float* __restrict__ t_ak, const float* __restrict__ amp,
    const float* __restrict__ t_ar, const float* __restrict__ b_out,
    unsigned* __restrict__ flags)
{
    __shared__ unsigned short Asm[2 * 5120];   // 2 planes x (80 x 64) bf16
    __shared__ unsigned short Bsm[2 * 2048];   // 2 planes x (32 x 64) bf16
    __shared__ float Csm[2 * 2640];            // 2 kh-planes x (80 x 33) fp32

    const int tid  = threadIdx.x, blk = blockIdx.x;
    const int wave = tid >> 6, lane = tid & 63;
    const int m16  = lane & 15, quad = lane >> 4;
    const int kh   = wave >> 1, jt = wave & 1;
    const int kq   = kh * 4 + quad;            // k-slot 0..7 within 64-k tile
    const int sr   = lane >> 3, sc = lane & 7;
    const int btile = blk & 15, ntile = blk >> 4;
    const int n0 = ntile * 32, r0 = btile * 80;
    const int chalf = ntile >> 4, octile = ntile & 15;
    const int oc0 = octile * 32, rlo = chalf * 5;

    f32x4 acc[5];

    auto zero_acc = [&]() {
#pragma unroll
        for (int i = 0; i < 5; i++) acc[i] = (f32x4){0.f, 0.f, 0.f, 0.f};
    };
    auto stageA = [&](const unsigned short* src, int ld, int plane) {
#pragma unroll
        for (int g0 = 0; g0 < 12; g0 += 4) {
            int g = g0 + wave;
            if (g < 10) {
                int r = g * 8 + sr;
                gl_lds16(src + (size_t)r * ld + (sc ^ (r & 7)) * 8,
                         Asm + plane * 5120 + g * 512);
            }
        }
    };
    auto stageB = [&](const unsigned short* src, int ld, int plane) {
        int r = wave * 8 + sr;
        gl_lds16(src + (size_t)r * ld + (sc ^ (r & 7)) * 8,
                 Bsm + plane * 2048 + wave * 512);
    };
    auto compute = [&](int plane) {
        const unsigned short* Ap = Asm + plane * 5120;
        const unsigned short* Bp = Bsm + plane * 2048;
        int rb = jt * 16 + m16;
        ushortx8 bfrag = *(const ushortx8*)(Bp + rb * 64 + ((kq ^ (rb & 7)) * 8));
        ushortx8 a5[5];
#pragma unroll
        for (int i = 0; i < 5; i++) {
            int ra = i * 16 + m16;
            a5[i] = *(const ushortx8*)(Ap + ra * 64 + ((kq ^ (ra & 7)) * 8));
        }
#pragma unroll
        for (int i = 0; i < 5; i++)
            acc[i] = __builtin_amdgcn_mfma_f32_16x16x32_bf16(
                __builtin_bit_cast(bf16x8, a5[i]),
                __builtin_bit_cast(bf16x8, bfrag), acc[i], 0, 0, 0);
    };
    auto run_tiles = [&](const unsigned short* As, int lda,
                         const unsigned short* Bs, int ldb, int nk) {
        stageA(As, lda, 0);
        stageB(Bs, ldb, 0);
        __syncthreads();
        for (int kk = 0; kk < nk; kk++) {
            int cur = kk & 1;
            if (kk + 1 < nk) {
                stageA(As + (kk + 1) * 64, lda, cur ^ 1);
                stageB(Bs + (kk + 1) * 64, ldb, cur ^ 1);
            }
            compute(cur);
            __syncthreads();
        }
    };
    auto acc_to_csm = [&]() {
        float* Cp = Csm + kh * 2640;
#pragma unroll
        for (int i = 0; i < 5; i++)
#pragma unroll
            for (int v = 0; v < 4; v++)
                Cp[(i * 16 + quad * 4 + v) * 33 + jt * 16 + m16] = acc[i][v];
    };

    // ---- GLIFR per-thread state: tid<128 owns (btile*4+bl, n0+hl) ----
    const int bl = (tid >> 5) & 3, hl = tid & 31;
    const int h  = n0 + hl;
    const float th  = thresh[h];
    const float sm  = sigmoidf(t_km[h]);
    const float rm  = 0.1f * sm, om = 1.f - sm;
    const float sa0 = sigmoidf(t_ak[h]),  sa1 = sigmoidf(t_ak[1024 + h]);
    const float am0 = amp[h],             am1 = amp[1024 + h];
    const float rr0 = 1.f - 2.f * sigmoidf(t_ar[h]);
    const float rr1 = 1.f - 2.f * sigmoidf(t_ar[1024 + h]);
    float volt = 0.f, a0 = 0.f, a1 = 0.f, fir = 0.f;

    auto readout = [&](int r) {
        zero_acc();
        run_tiles(F + (size_t)(r * 1280 + r0) * 1024, 1024,
                  WoutB + (size_t)oc0 * 1024, 1024, 16);
        acc_to_csm();
        __syncthreads();
        if (tid < 128) {
            float bv = b_out[oc0 + hl];
#pragma unroll
            for (int s = 0; s < 20; s++) {
                float v = Csm[(bl * 20 + s) * 33 + hl]
                        + Csm[2640 + (bl * 20 + s) * 33 + hl] + bv;
                int b = btile * 4 + bl, t = r * 20 + s;
                out[((size_t)b * 200 + t) * 512 + oc0 + hl] = v;
            }
        }
        __syncthreads();
    };

    for (int c = 0; c < 10; c++) {
        zero_acc();
        // input-projection part (no cross-block dependency)
        run_tiles(xb + (size_t)(c * 1280 + r0) * 512, 512,
                  WinT + (size_t)n0 * 512, 512, 8);
        if (c > 0) {
            if (tid == 0) {
                unsigned* fl = flags + (c - 1) * 16 + btile;
                while (__hip_atomic_load(fl, __ATOMIC_RELAXED,
                                         __HIP_MEMORY_SCOPE_AGENT) < 32u)
                    __builtin_amdgcn_s_sleep(4);
                (void)__hip_atomic_load(fl, __ATOMIC_ACQUIRE,
                                        __HIP_MEMORY_SCOPE_AGENT);
            }
            __syncthreads();
            run_tiles(F + (size_t)((c - 1) * 1280 + r0) * 1024, 1024,
                      WlatT + (size_t)n0 * 1024, 1024, 16);
        }
        acc_to_csm();
        __syncthreads();
        if (tid < 128) {
#pragma unroll
            for (int s = 0; s < 20; s++) {
                float sv = Csm[(bl * 20 + s) * 33 + hl]
                         + Csm[2640 + (bl * 20 + s) * 33 + hl];
                float na0 = (am0 + rr0 * a0) * fir * sa0 + (1.f - sa0) * a0;
                float na1 = (am1 + rr1 * a1) * fir * sa1 + (1.f - sa1) * a1;
                volt = rm * (sv + na0 + na1) + om * volt;
                fir  = sigmoidf(volt - th);
                F[(size_t)(c * 1280 + r0 + bl * 20 + s) * 1024 + h] = f2b(fir);
                a0 = na0; a1 = na1;
            }
        }
        __syncthreads();
        if (tid == 0)
            __hip_atomic_fetch_add(flags + c * 16 + btile, 1u,
                                   __ATOMIC_RELEASE, __HIP_MEMORY_SCOPE_AGENT);
        // interleaved readout: chunk c-1's F is complete (we waited on it)
        int r = c - 1;
        if (r >= rlo && r < rlo + 5) readout(r);
    }
    // tail: chunk-half 1 blocks still owe readout of chunk 9
    if (chalf == 1) {
        if (tid == 0) {
            unsigned* fl = flags + 9 * 16 + btile;
            while (__hip_atomic_load(fl, __ATOMIC_RELAXED,
                                     __HIP_MEMORY_SCOPE_AGENT) < 32u)
                __builtin_amdgcn_s_sleep(4);
            (void)__hip_atomic_load(fl, __ATOMIC_ACQUIRE,
                                    __HIP_MEMORY_SCOPE_AGENT);
        }
        __syncthreads();
        readout(9);
    }
}

// ---------------------------------------------------------------------------
extern "C" void kernel_launch(void* const* d_in, const int* in_sizes, int n_in,
                              void* d_out, int out_size, void* d_ws, size_t ws_size,
                              hipStream_t stream)
{
    const float* x      = (const float*)d_in[0];  // [64,200,512]
    const float* W_in   = (const float*)d_in[1];  // [512,1024]
    const float* W_lat  = (const float*)d_in[2];  // [1024,1024]
    const float* thresh = (const float*)d_in[3];  // [1,1024]
    const float* t_km   = (const float*)d_in[4];  // [1,1024]
    const float* t_ak   = (const float*)d_in[5];  // [2,1,1024]
    const float* amp    = (const float*)d_in[6];  // [2,1,1024]
    const float* t_ar   = (const float*)d_in[7];  // [2,1,1024]
    const float* W_out  = (const float*)d_in[8];  // [512,1024] (n,k)
    const float* b_out  = (const float*)d_in[9];  // [512]
    float* out = (float*)d_out;                   // [64,200,512]

    char* ws = (char*)d_ws;
    unsigned short* F     = (unsigned short*)ws;
    unsigned short* xb    = (unsigned short*)(ws + 26214400);
    unsigned short* WinT  = (unsigned short*)(ws + 39321600);
    unsigned short* WlatT = (unsigned short*)(ws + 40370176);
    unsigned short* WoutB = (unsigned short*)(ws + 42467328);
    unsigned*       flags = (unsigned*)(ws + 43515904);

    prep<<<4097, 256, 0, stream>>>(x, W_in, W_lat, W_out,
                                   xb, WinT, WlatT, WoutB, flags);
    fused<<<512, 256, 0, stream>>>(xb, WinT, WlatT, WoutB, F, out,
                                   thresh, t_km, t_ak, amp, t_ar, b_out, flags);
}

// Round 8
// 326.420 us; speedup vs baseline: 1.5061x; 1.5061x over previous
//
#include <hip/hip_runtime.h>

// GLIFR RNN (B=64, T=200, IN=512, HID=1024, OUT=512), fp32 in/out, bf16 MFMA.
//
// Round 8: LDS-free GEMM in the fused chain. Rounds 6/7 showed the per-k-tile
// __syncthreads drain (vmcnt(0) on just-issued global_load_lds) costs
// ~700-900 cy x 24 tiles x 10 chunks with no co-resident block to cover it.
// Here MFMA fragments are loaded global->VGPR directly (lane m16,quad loads
// A[row][wave*32+quad*8 ..+8]; per instr = 16 rows x 64 contiguous B, fully
// consumed lines). Waves split K 4-ways (BK=128, zero A duplication); K-loop
// has NO barriers, so the compiler pipelines loads across tiles with partial
// vmcnt waits. Partials merged once per chunk via padded Csm (2 planes,
// waves 2,3 add into 0,1). Readout = separate kernel (round 7's interleave
// sat on the critical path). Flags identical to round 6 (proven).
//
// Workspace (~44 MB):
//   F     bf16 [10][1280][1024] @ 0          (26214400 B)  rows b*20+s
//   xb    bf16 [10][1280][512]  @ 26214400   (13107200 B)  rows b*20+s
//   WinT  bf16 [1024][512]      @ 39321600   (1048576 B)
//   WlatT bf16 [1024][1024]     @ 40370176   (2097152 B)
//   WoutB bf16 [512][1024]      @ 42467328   (1048576 B)
//   flags u32  [10][16]+pad     @ 43515904   (1024 B)   count to 16

typedef float f32x4 __attribute__((ext_vector_type(4)));
typedef __bf16 bf16x8 __attribute__((ext_vector_type(8)));
typedef unsigned short ushortx8 __attribute__((ext_vector_type(8)));
typedef unsigned short ushortx4 __attribute__((ext_vector_type(4)));

__device__ __forceinline__ unsigned short f2b(float f) {
    unsigned int u = __float_as_uint(f);
    unsigned int r = u + 0x7FFFu + ((u >> 16) & 1u);   // RNE
    return (unsigned short)(r >> 16);
}
__device__ __forceinline__ float sigmoidf(float x) {
    return 1.0f / (1.0f + __expf(-x));
}

// async global->LDS (readout kernel only)
__device__ __forceinline__ void gl_lds16(const unsigned short* g, unsigned short* l) {
    __builtin_amdgcn_global_load_lds(
        (const __attribute__((address_space(1))) void*)g,
        (__attribute__((address_space(3))) void*)l, 16, 0, 0);
}

// ---------------------------------------------------------------------------
// prep: W_in/W_lat transpose->bf16, W_out convert, x->xb reorder, flags zero.
// ---------------------------------------------------------------------------
__global__ __launch_bounds__(256) void prep(
    const float* __restrict__ x, const float* __restrict__ W_in,
    const float* __restrict__ W_lat, const float* __restrict__ W_out,
    unsigned short* __restrict__ xb, unsigned short* __restrict__ WinT,
    unsigned short* __restrict__ WlatT, unsigned short* __restrict__ WoutB,
    unsigned* __restrict__ flags)
{
    __shared__ unsigned short t[64][65];
    const int blk = blockIdx.x;
    if (blk < 384) {
        const float* in; unsigned short* outp; int R, C, bx, by;
        if (blk < 128) { in = W_in;  outp = WinT;  R = 512;  C = 1024;
                         bx = (blk & 15) * 64; by = (blk >> 4) * 64; }
        else { int i = blk - 128; in = W_lat; outp = WlatT; R = 1024; C = 1024;
               bx = (i & 15) * 64; by = (i >> 4) * 64; }
        int tx = threadIdx.x & 63, ty = threadIdx.x >> 6;
        for (int r = ty; r < 64; r += 4)
            t[r][tx] = f2b(in[(size_t)(by + r) * C + bx + tx]);
        __syncthreads();
        for (int r = ty; r < 64; r += 4)
            outp[(size_t)(bx + r) * R + by + tx] = t[tx][r];
    } else if (blk < 896) {
        int i = ((blk - 384) * 256 + threadIdx.x) * 4;     // 512*1024 elems
        f32x4 v = *(const f32x4*)(W_out + i);
        ushortx4 o;
        o[0] = f2b(v[0]); o[1] = f2b(v[1]); o[2] = f2b(v[2]); o[3] = f2b(v[3]);
        *(ushortx4*)(WoutB + i) = o;
    } else if (blk < 4096) {
        size_t i8 = (size_t)((blk - 896) * 256 + threadIdx.x) * 8;
        int g = (int)(i8 >> 9), k = (int)(i8 & 511);
        int c = g / 1280, rr = g - c * 1280, b = rr / 20, s = rr - b * 20;
        const float* src = x + ((size_t)b * 200 + c * 20 + s) * 512 + k;
        f32x4 v0 = *(const f32x4*)src, v1 = *(const f32x4*)(src + 4);
        ushortx8 o;
        o[0] = f2b(v0[0]); o[1] = f2b(v0[1]); o[2] = f2b(v0[2]); o[3] = f2b(v0[3]);
        o[4] = f2b(v1[0]); o[5] = f2b(v1[1]); o[6] = f2b(v1[2]); o[7] = f2b(v1[3]);
        *(ushortx8*)(xb + i8) = o;
    } else {
        flags[threadIdx.x] = 0u;
    }
}

// ---------------------------------------------------------------------------
// Barrier-free GEMM part: NK tiles of BK=128; this wave contributes the
// k-window [kt*128 + wave*32, +32) via fragments loaded straight to VGPRs.
// 1-tile-ahead register prefetch; compiler inserts partial vmcnt waits.
// ---------------------------------------------------------------------------
template<int NK>
__device__ __forceinline__ void gemm_part(
    const unsigned short* __restrict__ Ab, int lda,
    const unsigned short* __restrict__ Bb, int ldb,
    int m16, int kofs, f32x4 (&acc)[5][4])
{
    ushortx8 a[2][5], b[2][4];
#pragma unroll
    for (int i = 0; i < 5; i++)
        a[0][i] = *(const ushortx8*)(Ab + (size_t)(i * 16 + m16) * lda + kofs);
#pragma unroll
    for (int j = 0; j < 4; j++)
        b[0][j] = *(const ushortx8*)(Bb + (size_t)(j * 16 + m16) * ldb + kofs);
#pragma unroll
    for (int kt = 0; kt < NK; kt++) {
        const int cur = kt & 1, nxt = cur ^ 1;
        if (kt + 1 < NK) {
            const int ko = (kt + 1) * 128 + kofs;
#pragma unroll
            for (int i = 0; i < 5; i++)
                a[nxt][i] = *(const ushortx8*)(Ab + (size_t)(i * 16 + m16) * lda + ko);
#pragma unroll
            for (int j = 0; j < 4; j++)
                b[nxt][j] = *(const ushortx8*)(Bb + (size_t)(j * 16 + m16) * ldb + ko);
        }
#pragma unroll
        for (int i = 0; i < 5; i++)
#pragma unroll
            for (int j = 0; j < 4; j++)
                acc[i][j] = __builtin_amdgcn_mfma_f32_16x16x32_bf16(
                    __builtin_bit_cast(bf16x8, a[cur][i]),
                    __builtin_bit_cast(bf16x8, b[cur][j]),
                    acc[i][j], 0, 0, 0);
    }
}

// ---------------------------------------------------------------------------
// Fused GLIFR chain. 256 blocks x 256 threads (1/CU). Block (btile,ntile)
// owns 80 rows (4 b x 20 s) x 64 h per chunk. Per chunk: proj part (K=512,
// no dep) -> flag wait -> lateral part (K=1024) -> Csm merge (2 planes,
// stride 65) -> 20-step recurrence (all 256 threads own 4b x 64h states)
// -> F store -> release flag.
// ---------------------------------------------------------------------------
__global__ __launch_bounds__(256, 1) void fused(
    const unsigned short* __restrict__ xb,
    const unsigned short* __restrict__ WinT,
    const unsigned short* __restrict__ WlatT,
    unsigned short* __restrict__ F,
    const float* __restrict__ thresh, const float* __restrict__ t_km,
    const float* __restrict__ t_ak, const float* __restrict__ amp,
    const float* __restrict__ t_ar,
    unsigned* __restrict__ flags)
{
    __shared__ float Csm[2 * 5200];            // 2 planes x (80 x 65) fp32

    const int tid  = threadIdx.x, blk = blockIdx.x;
    const int wave = tid >> 6, lane = tid & 63;
    const int m16  = lane & 15, quad = lane >> 4;
    const int kofs = wave * 32 + quad * 8;     // this wave's k-window slot
    const int btile = blk & 15, ntile = blk >> 4;
    const int n0 = ntile * 64, r0 = btile * 80;

    f32x4 acc[5][4];

    // ---- GLIFR per-thread state: (batch btile*4+wave, hidden n0+lane) ----
    const int h = n0 + lane;
    const float th  = thresh[h];
    const float sm  = sigmoidf(t_km[h]);
    const float rm  = 0.1f * sm, om = 1.f - sm;
    const float sa0 = sigmoidf(t_ak[h]),  sa1 = sigmoidf(t_ak[1024 + h]);
    const float am0 = amp[h],             am1 = amp[1024 + h];
    const float rr0 = 1.f - 2.f * sigmoidf(t_ar[h]);
    const float rr1 = 1.f - 2.f * sigmoidf(t_ar[1024 + h]);
    float volt = 0.f, a0 = 0.f, a1 = 0.f, fir = 0.f;

    for (int c = 0; c < 10; c++) {
#pragma unroll
        for (int i = 0; i < 5; i++)
#pragma unroll
            for (int j = 0; j < 4; j++)
                acc[i][j] = (f32x4){0.f, 0.f, 0.f, 0.f};

        // proj part (K=512, 4 tiles) — no cross-block dependency
        gemm_part<4>(xb + (size_t)(c * 1280 + r0) * 512, 512,
                     WinT + (size_t)n0 * 512, 512, m16, kofs, acc);

        if (c > 0) {
            if (tid == 0) {
                unsigned* fl = flags + (c - 1) * 16 + btile;
                while (__hip_atomic_load(fl, __ATOMIC_RELAXED,
                                         __HIP_MEMORY_SCOPE_AGENT) < 16u)
                    __builtin_amdgcn_s_sleep(1);
                (void)__hip_atomic_load(fl, __ATOMIC_ACQUIRE,
                                        __HIP_MEMORY_SCOPE_AGENT);
            }
            __syncthreads();
            // lateral part (K=1024, 8 tiles)
            gemm_part<8>(F + (size_t)((c - 1) * 1280 + r0) * 1024, 1024,
                         WlatT + (size_t)n0 * 1024, 1024, m16, kofs, acc);
        }

        // ---- merge 4 k-quarter partials into 2 Csm planes ----
        {
            float* Cp = Csm + (wave & 1) * 5200;
            if (wave < 2) {
#pragma unroll
                for (int i = 0; i < 5; i++)
#pragma unroll
                    for (int j = 0; j < 4; j++)
#pragma unroll
                        for (int v = 0; v < 4; v++)
                            Cp[(i * 16 + quad * 4 + v) * 65 + j * 16 + m16]
                                = acc[i][j][v];
            }
            __syncthreads();
            if (wave >= 2) {
#pragma unroll
                for (int i = 0; i < 5; i++)
#pragma unroll
                    for (int j = 0; j < 4; j++)
#pragma unroll
                        for (int v = 0; v < 4; v++)
                            Cp[(i * 16 + quad * 4 + v) * 65 + j * 16 + m16]
                                += acc[i][j][v];
            }
            __syncthreads();
        }

        // ---- 20-step recurrence; all 256 threads; state in registers ----
        {
            const int bl = wave, hl = lane;
#pragma unroll
            for (int s = 0; s < 20; s++) {
                float sv = Csm[(bl * 20 + s) * 65 + hl]
                         + Csm[5200 + (bl * 20 + s) * 65 + hl];
                float na0 = (am0 + rr0 * a0) * fir * sa0 + (1.f - sa0) * a0;
                float na1 = (am1 + rr1 * a1) * fir * sa1 + (1.f - sa1) * a1;
                volt = rm * (sv + na0 + na1) + om * volt;
                fir  = sigmoidf(volt - th);
                F[(size_t)(c * 1280 + r0 + bl * 20 + s) * 1024 + h] = f2b(fir);
                a0 = na0; a1 = na1;
            }
        }
        __syncthreads();
        if (tid == 0)
            __hip_atomic_fetch_add(flags + c * 16 + btile, 1u,
                                   __ATOMIC_RELEASE, __HIP_MEMORY_SCOPE_AGENT);
    }
}

// ---------------------------------------------------------------------------
// Readout GEMM: out = F @ WoutB^T + b_out. 128x128 tiles, global_load_lds
// staging with XOR swizzle (round-3 proven). Epilogue remaps F row order
// (c*1280 + b*20 + s) -> out[b][t=c*20+s][col].
// ---------------------------------------------------------------------------
__global__ __launch_bounds__(256) void readout(
    const unsigned short* __restrict__ A,
    const unsigned short* __restrict__ Bt,
    float* __restrict__ outf,
    const float* __restrict__ bias)
{
    constexpr int BM = 128, BN = 128, K = 1024, N = 512;
    __shared__ unsigned short Asm[BM * 64];
    __shared__ unsigned short Bsm[BN * 64];

    const int tid  = threadIdx.x;
    const int wave = tid >> 6, lane = tid & 63;
    const int m16  = lane & 15, quad = lane >> 4;
    const int bm0  = blockIdx.y * BM, bn0 = blockIdx.x * BN;
    const int wr   = (wave >> 1) * 64, wc = (wave & 1) * 64;
    const int sr   = lane >> 3, sc = lane & 7;

    f32x4 acc[4][4];
#pragma unroll
    for (int i = 0; i < 4; i++)
#pragma unroll
        for (int j = 0; j < 4; j++)
            acc[i][j] = (f32x4){0.f, 0.f, 0.f, 0.f};

    for (int k0 = 0; k0 < K; k0 += 64) {
#pragma unroll
        for (int g = wave; g < 16; g += 4) {
            int r = g * 8 + sr, c = sc ^ (r & 7);
            gl_lds16(A + (size_t)(bm0 + r) * K + k0 + c * 8, Asm + g * 512);
        }
#pragma unroll
        for (int g = wave; g < 16; g += 4) {
            int r = g * 8 + sr, c = sc ^ (r & 7);
            gl_lds16(Bt + (size_t)(bn0 + r) * K + k0 + c * 8, Bsm + g * 512);
        }
        __syncthreads();

        ushortx8 af[2][4], bfr[2][4];
#pragma unroll
        for (int kh = 0; kh < 2; kh++) {
#pragma unroll
            for (int i = 0; i < 4; i++) {
                int ra = wr + i * 16 + m16;
                af[kh][i] = *(const ushortx8*)(
                    Asm + ra * 64 + (((kh * 4 + quad) ^ (ra & 7)) * 8));
            }
#pragma unroll
            for (int j = 0; j < 4; j++) {
                int rb = wc + j * 16 + m16;
                bfr[kh][j] = *(const ushortx8*)(
                    Bsm + rb * 64 + (((kh * 4 + quad) ^ (rb & 7)) * 8));
            }
        }
#pragma unroll
        for (int i = 0; i < 4; i++)
#pragma unroll
            for (int j = 0; j < 4; j++) {
                acc[i][j] = __builtin_amdgcn_mfma_f32_16x16x32_bf16(
                    __builtin_bit_cast(bf16x8, af[0][i]),
                    __builtin_bit_cast(bf16x8, bfr[0][j]),
                    acc[i][j], 0, 0, 0);
                acc[i][j] = __builtin_amdgcn_mfma_f32_16x16x32_bf16(
                    __builtin_bit_cast(bf16x8, af[1][i]),
                    __builtin_bit_cast(bf16x8, bfr[1][j]),
                    acc[i][j], 0, 0, 0);
            }
        __syncthreads();
    }

#pragma unroll
    for (int i = 0; i < 4; i++)
#pragma unroll
        for (int j = 0; j < 4; j++) {
            int col = bn0 + wc + j * 16 + m16;
            float bv = bias[col];
#pragma unroll
            for (int v = 0; v < 4; v++) {
                int row = bm0 + wr + i * 16 + quad * 4 + v;
                int c = row / 1280, r = row - c * 1280;
                int b = r / 20, s = r - b * 20, t = c * 20 + s;
                outf[((size_t)b * 200 + t) * N + col] = acc[i][j][v] + bv;
            }
        }
}

// ---------------------------------------------------------------------------
extern "C" void kernel_launch(void* const* d_in, const int* in_sizes, int n_in,
                              void* d_out, int out_size, void* d_ws, size_t ws_size,
                              hipStream_t stream)
{
    const float* x      = (const float*)d_in[0];  // [64,200,512]
    const float* W_in   = (const float*)d_in[1];  // [512,1024]
    const float* W_lat  = (const float*)d_in[2];  // [1024,1024]
    const float* thresh = (const float*)d_in[3];  // [1,1024]
    const float* t_km   = (const float*)d_in[4];  // [1,1024]
    const float* t_ak   = (const float*)d_in[5];  // [2,1,1024]
    const float* amp    = (const float*)d_in[6];  // [2,1,1024]
    const float* t_ar   = (const float*)d_in[7];  // [2,1,1024]
    const float* W_out  = (const float*)d_in[8];  // [512,1024] (n,k)
    const float* b_out  = (const float*)d_in[9];  // [512]
    float* out = (float*)d_out;                   // [64,200,512]

    char* ws = (char*)d_ws;
    unsigned short* F     = (unsigned short*)ws;
    unsigned short* xb    = (unsigned short*)(ws + 26214400);
    unsigned short* WinT  = (unsigned short*)(ws + 39321600);
    unsigned short* WlatT = (unsigned short*)(ws + 40370176);
    unsigned short* WoutB = (unsigned short*)(ws + 42467328);
    unsigned*       flags = (unsigned*)(ws + 43515904);

    prep<<<4097, 256, 0, stream>>>(x, W_in, W_lat, W_out,
                                   xb, WinT, WlatT, WoutB, flags);
    fused<<<256, 256, 0, stream>>>(xb, WinT, WlatT, F,
                                   thresh, t_km, t_ak, amp, t_ar, flags);
    readout<<<dim3(4, 100), 256, 0, stream>>>(F, WoutB, out, b_out);
}